// Round 5
// baseline (321.458 us; speedup 1.0000x reference)
//
#include <hip/hip_runtime.h>
#include <stdint.h>

// B=4, M=4096, HID=1024, H=16, HD=64, SEG=128, nseg=32, DIL=2, SCALE=0.125
// out = ((perm-gathered x) @ Wqkv^T -> segment attention with parity mask) @ Wout^T

typedef __attribute__((ext_vector_type(8))) short short8;
typedef __attribute__((ext_vector_type(4))) short short4v;
typedef __attribute__((ext_vector_type(4))) float f32x4;

#define DEV __device__ __forceinline__

DEV short f2bf(float f) {
  union { float f; uint32_t u; } x; x.f = f;
  uint32_t r = x.u + 0x7fffu + ((x.u >> 16) & 1u);
  return (short)(r >> 16);
}

DEV short4v pack4(f32x4 v) {
  short4v o = { f2bf(v[0]), f2bf(v[1]), f2bf(v[2]), f2bf(v[3]) };
  return o;
}

DEV void gload_lds16(const void* g, void* l) {
  __builtin_amdgcn_global_load_lds(
      (const __attribute__((address_space(1))) uint32_t*)g,
      (__attribute__((address_space(3))) uint32_t*)l, 16, 0, 0);
}

#define BAR() __builtin_amdgcn_s_barrier()
#define LGKM0() do { asm volatile("s_waitcnt lgkmcnt(0)" ::: "memory"); \
                     __builtin_amdgcn_sched_barrier(0); } while (0)
#define VMC(n) asm volatile("s_waitcnt vmcnt(" #n ")" ::: "memory")

// ---------------- converts ----------------
__global__ __launch_bounds__(256) void k_gather_cast(
    const float* __restrict__ x, const int* __restrict__ perm, short* __restrict__ xp) {
  const int row = blockIdx.x;             // b*4096 + pos (permuted order)
  const int b = row >> 12, pos = row & 4095;
  const int src = (b << 12) + perm[pos];
  const f32x4 v = ((const f32x4*)(x + (size_t)src * 1024))[threadIdx.x];
  ((short4v*)(xp + (size_t)row * 1024))[threadIdx.x] = pack4(v);
}

__global__ __launch_bounds__(256) void k_cast(
    const float* __restrict__ src, short* __restrict__ dst) {
  const int i = blockIdx.x * 256 + threadIdx.x;
  const f32x4 v = ((const f32x4*)src)[i];
  ((short4v*)dst)[i] = pack4(v);
}

// ---------------- 256x256 8-phase GEMM (GEMM1): C = A(MxK) * W(NxK)^T, K=1024 ----------------
// 8 waves 2(M)x4(N). mfma(b-frag, a-frag): C-frag rows = gc (4lg+reg), cols = gr (lrow)
// -> acc regs hold 4 consecutive output COLUMNS -> packed epilogue stores.
// LDS: 2 dbuf x (A 256x64 + B 256x64) bf16 = 128 KiB, T2-swizzled via pre-swizzled src.
// Depth-2 prefetch (round-2 choreography): vmcnt(4) once per K-tile.
// EPI==0: packed-b64 scatter into qkv ws (3,B,H,M,HD). EPI==1: fp32 b128, N=1024.
template <int EPI, int NBJ>
__global__ __launch_bounds__(512, 2) void k_gemm8(
    const short* __restrict__ A, const short* __restrict__ W, void* __restrict__ Cout) {
  __shared__ __attribute__((aligned(16))) short lds[65536];   // 128 KiB
  const int tid = threadIdx.x;
  const int lane = tid & 63, w = tid >> 6;
  const int wr = w >> 2, wc = w & 3;
  const int lrow = lane & 15, lg = lane >> 4;

  // XCD-aware swizzle (grid = NBJ*64, divisible by 8)
  const int nwg = NBJ * 64;
  const int cpx = nwg >> 3;
  const int bid = blockIdx.x;
  const int sw = (bid & 7) * cpx + (bid >> 3);
  const int bi = sw / NBJ, bj = sw % NBJ;

  const short* Abase = A + (size_t)bi * 256 * 1024;
  const short* Bbase = W + (size_t)bj * 256 * 1024;

  // staging: 2 x 16B chunks per thread per 128x64 half-tile
  const int c0 = tid, c1 = tid + 512;
  const int sOff0 = (c0 >> 3) * 1024 + (((c0 & 7) ^ ((c0 >> 3) & 7)) * 8);
  const int sOff1 = (c1 >> 3) * 1024 + (((c1 & 7) ^ ((c1 >> 3) & 7)) * 8);
  const int pc0 = lg ^ (lrow & 7), pc1 = (4 + lg) ^ (lrow & 7);

  f32x4 acc[2][2][2][4] = {};   // [nh][ni][mh][mi]
  short8 af[4][2], bfrag[2][2][2];

#define ISSUE(base, half, tile, isB) do {                                   \
    const short* _s = (base) + (half) * (128 * 1024) + (tile) * 64;         \
    short* _d = lds + (((tile) & 1) * 32768) + (isB) * 16384 + (half) * 8192; \
    gload_lds16(_s + sOff0, _d + c0 * 8);                                   \
    gload_lds16(_s + sOff1, _d + c1 * 8);                                   \
  } while (0)

#define LDA(mh) do {                                                        \
    const short* _b = ldsbuf + (mh) * 8192;                                 \
    _Pragma("unroll") for (int mi = 0; mi < 4; ++mi) {                      \
      const short* _r = _b + (wr * 64 + mi * 16 + lrow) * 64;               \
      af[mi][0] = *(const short8*)(_r + pc0 * 8);                           \
      af[mi][1] = *(const short8*)(_r + pc1 * 8); } } while (0)

#define LDB(nh) do {                                                        \
    const short* _b = ldsbuf + 16384 + (nh) * 8192;                         \
    _Pragma("unroll") for (int ni = 0; ni < 2; ++ni) {                      \
      const short* _r = _b + (wc * 32 + ni * 16 + lrow) * 64;               \
      bfrag[nh][ni][0] = *(const short8*)(_r + pc0 * 8);                    \
      bfrag[nh][ni][1] = *(const short8*)(_r + pc1 * 8); } } while (0)

  // operand order: mfma(bfrag, af) -> C rows = gc-side, cols = gr-side
#define MM(mh, nh) do {                                                     \
    _Pragma("unroll") for (int ni = 0; ni < 2; ++ni)                        \
    _Pragma("unroll") for (int mi = 0; mi < 4; ++mi) {                      \
      acc[nh][ni][mh][mi] = __builtin_amdgcn_mfma_f32_16x16x32_bf16(        \
          bfrag[nh][ni][0], af[mi][0], acc[nh][ni][mh][mi], 0, 0, 0);       \
      acc[nh][ni][mh][mi] = __builtin_amdgcn_mfma_f32_16x16x32_bf16(        \
          bfrag[nh][ni][1], af[mi][1], acc[nh][ni][mh][mi], 0, 0, 0); } } while (0)

  // prologue: tile0 {A0,B0,A1,B1} + tile1 {A0,B0}; wait tile0, 2 half-tiles in flight
  ISSUE(Abase, 0, 0, 0); ISSUE(Bbase, 0, 0, 1);
  ISSUE(Abase, 1, 0, 0); ISSUE(Bbase, 1, 0, 1);
  ISSUE(Abase, 0, 1, 0); ISSUE(Bbase, 0, 1, 1);
  VMC(4);
  BAR();

#pragma unroll 2
  for (int t = 0; t < 16; ++t) {
    const short* ldsbuf = lds + ((t & 1) * 32768);
    // ph1: (mh0,nh0); prefetch A1(t+1)
    LDA(0); LDB(0);
    if (t < 15) ISSUE(Abase, 1, t + 1, 0);
    BAR(); LGKM0();
    __builtin_amdgcn_s_setprio(1); MM(0, 0); __builtin_amdgcn_s_setprio(0);
    BAR();
    // ph2: (mh0,nh1); prefetch B1(t+1)
    LDB(1);
    if (t < 15) ISSUE(Bbase, 1, t + 1, 1);
    BAR(); LGKM0();
    __builtin_amdgcn_s_setprio(1); MM(0, 1); __builtin_amdgcn_s_setprio(0);
    BAR();
    // ph3: (mh1,nh0); prefetch A0(t+2) into current buf (A0 LDS dead since ph1)
    LDA(1);
    if (t < 14) ISSUE(Abase, 0, t + 2, 0);
    BAR(); LGKM0();
    __builtin_amdgcn_s_setprio(1); MM(1, 0); __builtin_amdgcn_s_setprio(0);
    BAR();
    // ph4: (mh1,nh1); prefetch B0(t+2); counted vmcnt(4) certifies tile t+1 resident
    if (t < 14) ISSUE(Bbase, 0, t + 2, 1);
    BAR(); LGKM0();
    __builtin_amdgcn_s_setprio(1); MM(1, 1); __builtin_amdgcn_s_setprio(0);
    if (t < 14) { VMC(4); } else { VMC(0); }
    BAR();
  }
#undef ISSUE
#undef LDA
#undef LDB
#undef MM

  if (EPI == 0) {
    short* Q = (short*)Cout;
    const int bb = bi >> 4;
    const int posc = (bi & 15) * 256 + wr * 64 + lrow;
#pragma unroll
    for (int nh = 0; nh < 2; ++nh)
#pragma unroll
    for (int ni = 0; ni < 2; ++ni) {
      const int gc0 = bj * 256 + nh * 128 + wc * 32 + ni * 16;   // 16-aligned
      const int sel = gc0 >> 10, h = (gc0 >> 6) & 15;
      const int dbase = (gc0 & 63) + 4 * lg;
      short* basep = Q + (((size_t)(sel * 4 + bb) * 16 + h) << 18) + dbase;
#pragma unroll
      for (int mh = 0; mh < 2; ++mh)
#pragma unroll
      for (int mi = 0; mi < 4; ++mi) {
        const int pos = posc + mh * 128 + mi * 16;
        *(short4v*)(basep + (size_t)pos * 64) = pack4(acc[nh][ni][mh][mi]);
      }
    }
  } else {
    float* C = (float*)Cout;
#pragma unroll
    for (int nh = 0; nh < 2; ++nh)
#pragma unroll
    for (int ni = 0; ni < 2; ++ni) {
      const int gcb = bj * 256 + nh * 128 + wc * 32 + ni * 16 + 4 * lg;
#pragma unroll
      for (int mh = 0; mh < 2; ++mh)
#pragma unroll
      for (int mi = 0; mi < 4; ++mi) {
        const int gr = bi * 256 + mh * 128 + wr * 64 + mi * 16 + lrow;
        *(f32x4*)(C + (size_t)gr * 1024 + gcb) = acc[nh][ni][mh][mi];
      }
    }
  }
}

// ---------------- 128x128 m97-style GEMM (GEMM2): C = A(16384xK) * W(1024xK)^T fp32 ----------------
// 4 waves, BK=64, single LDS buffer, syncthreads-bracketed gload_lds (m97 structure).
// Grid 1024 = 3 blocks/CU -> inter-block overlap covers the barrier drain.
__global__ __launch_bounds__(256, 3) void k_gemm_s(
    const short* __restrict__ A, const short* __restrict__ W, float* __restrict__ C) {
  __shared__ __attribute__((aligned(16))) short As[128 * 64];
  __shared__ __attribute__((aligned(16))) short Bs[128 * 64];
  const int tid = threadIdx.x;
  const int lane = tid & 63, w = tid >> 6;
  const int wr = w >> 1, wc = w & 1;
  const int lrow = lane & 15, lg = lane >> 4;
  // XCD swizzle over grid 1024; within an XCD chunk, all bj for a bi (A-panel L2 reuse)
  const int bid = blockIdx.x;
  const int sw = (bid & 7) * 128 + (bid >> 3);
  const int bi = sw >> 3, bj = sw & 7;

  f32x4 acc[4][4] = {};   // [ni][mi]
  const size_t arow0 = (size_t)bi * 128;
  const size_t brow0 = (size_t)bj * 128;

  for (int k0 = 0; k0 < 1024; k0 += 64) {
    __syncthreads();
#pragma unroll
    for (int i = 0; i < 4; ++i) {
      int c = i * 256 + tid;
      int row = c >> 3, ch = c & 7, g = ch ^ (row & 7);
      gload_lds16(A + (arow0 + row) * 1024 + k0 + g * 8, &As[c * 8]);
      gload_lds16(W + (brow0 + row) * 1024 + k0 + g * 8, &Bs[c * 8]);
    }
    __syncthreads();
#pragma unroll
    for (int kk = 0; kk < 2; ++kk) {
      short8 af[4], bf[4];
#pragma unroll
      for (int mi = 0; mi < 4; ++mi) {
        int r = wr * 64 + mi * 16 + lrow;
        int pc = (kk * 4 + lg) ^ (r & 7);
        af[mi] = *(const short8*)&As[r * 64 + pc * 8];
      }
#pragma unroll
      for (int ni = 0; ni < 4; ++ni) {
        int r = wc * 64 + ni * 16 + lrow;
        int pc = (kk * 4 + lg) ^ (r & 7);
        bf[ni] = *(const short8*)&Bs[r * 64 + pc * 8];
      }
#pragma unroll
      for (int ni = 0; ni < 4; ++ni)
#pragma unroll
        for (int mi = 0; mi < 4; ++mi)
          acc[ni][mi] = __builtin_amdgcn_mfma_f32_16x16x32_bf16(
              bf[ni], af[mi], acc[ni][mi], 0, 0, 0);
    }
  }
#pragma unroll
  for (int ni = 0; ni < 4; ++ni) {
    const int gcb = bj * 128 + wc * 64 + ni * 16 + 4 * lg;
#pragma unroll
    for (int mi = 0; mi < 4; ++mi) {
      const int gr = bi * 128 + wr * 64 + mi * 16 + lrow;
      *(f32x4*)(C + (size_t)gr * 1024 + gcb) = acc[ni][mi];
    }
  }
}

// ---------------- segment attention ----------------
// one block per (b,h,seg). S^T = mfma(K,Q): lane holds t = na*16+4lg+reg (4-runs),
// s = w*32+nb*16+lrow. Softmax over t = in-lane tree + shfl_xor(16,32).
// P stored row-major [s][t] with packed b64 (t-runs are contiguous), swizzled.
// O^T = mfma(Vt, P): lane holds d-runs -> packed b64 epilogue; inv is lane-local.
__global__ __launch_bounds__(256, 3) void k_attn(
    const short* __restrict__ qkv, short* __restrict__ aout) {
  __shared__ __attribute__((aligned(16))) short smem[24576];
  short* Qs = smem;
  short* Ks = smem + 8192;
  short* Vt = smem + 16384;   // transposed [d][t]
  short* Ps = smem;           // alias over Qs+Ks (dead after QK^T)
  const int bid = blockIdx.x;
  const int seg = bid & 31, h = (bid >> 5) & 15, b = bid >> 9;
  const size_t plane = (size_t)4096 * 64;
  const short* qp = qkv + ((size_t)(0 * 4 + b) * 16 + h) * plane + seg * 128 * 64;
  const short* kp = qkv + ((size_t)(1 * 4 + b) * 16 + h) * plane + seg * 128 * 64;
  const short* vp = qkv + ((size_t)(2 * 4 + b) * 16 + h) * plane + seg * 128 * 64;
  const int tid = threadIdx.x, lane = tid & 63, w = tid >> 6;
  const int lrow = lane & 15, lg = lane >> 4;

#pragma unroll
  for (int i = 0; i < 4; ++i) {
    int c = i * 256 + tid;
    int row = c >> 3, ch = c & 7, g = ch ^ (row & 7);
    gload_lds16(qp + row * 64 + g * 8, &Qs[c * 8]);
    gload_lds16(kp + row * 64 + g * 8, &Ks[c * 8]);
  }
  // V: coalesced 16B global loads, transposed+swizzled LDS writes
#pragma unroll
  for (int i = 0; i < 4; ++i) {
    int c = i * 256 + tid;
    int t = c >> 3, d0 = (c & 7) * 8;
    short8 v = *(const short8*)(vp + t * 64 + d0);
#pragma unroll
    for (int j = 0; j < 8; ++j) {
      int d = d0 + j;
      Vt[d * 128 + (t ^ ((d & 7) * 8))] = v[j];
    }
  }
  __syncthreads();

  // S^T = K Q^T : st[na][nb], C rows = t (K-side), cols = s (Q-side)
  f32x4 st[8][2] = {};
  __builtin_amdgcn_s_setprio(1);
#pragma unroll
  for (int kk = 0; kk < 2; ++kk) {
    short8 qb[2];
#pragma unroll
    for (int nb = 0; nb < 2; ++nb) {
      int r = w * 32 + nb * 16 + lrow;
      int pc = (kk * 4 + lg) ^ (r & 7);
      qb[nb] = *(const short8*)&Qs[r * 64 + pc * 8];
    }
#pragma unroll
    for (int na = 0; na < 8; ++na) {
      int r = na * 16 + lrow;
      int pc = (kk * 4 + lg) ^ (r & 7);
      short8 ka = *(const short8*)&Ks[r * 64 + pc * 8];
#pragma unroll
      for (int nb = 0; nb < 2; ++nb)
        st[na][nb] = __builtin_amdgcn_mfma_f32_16x16x32_bf16(ka, qb[nb], st[na][nb], 0, 0, 0);
    }
  }
  __builtin_amdgcn_s_setprio(0);

  // masked softmax over t (per lane: 32 t-values per s; s parity = lrow&1, t parity = reg&1)
  float inv_sm[2];
  const int oddS = lrow & 1;
#pragma unroll
  for (int nb = 0; nb < 2; ++nb) {
    float pm = -3.0e38f;
#pragma unroll
    for (int na = 0; na < 8; ++na)
#pragma unroll
      for (int reg = 0; reg < 4; ++reg) {
        float v = st[na][nb][reg] * 0.125f;
        if (oddS && (reg & 1)) v = -1.0e30f;
        st[na][nb][reg] = v;
        pm = fmaxf(pm, v);
      }
    pm = fmaxf(pm, __shfl_xor(pm, 16));
    pm = fmaxf(pm, __shfl_xor(pm, 32));
    float sum = 0.f;
#pragma unroll
    for (int na = 0; na < 8; ++na)
#pragma unroll
      for (int reg = 0; reg < 4; ++reg) {
        float p = __expf(st[na][nb][reg] - pm);
        st[na][nb][reg] = p;
        sum += p;
      }
    sum += __shfl_xor(sum, 16);
    sum += __shfl_xor(sum, 32);
    inv_sm[nb] = 1.0f / sum;
  }

  __syncthreads();   // all QK^T LDS reads done before Ps overwrites Qs/Ks

  // store P row-major [s][128 t], packed b64 (4 consecutive t per frag), swizzled
#pragma unroll
  for (int na = 0; na < 8; ++na)
#pragma unroll
    for (int nb = 0; nb < 2; ++nb) {
      const int s = w * 32 + nb * 16 + lrow;
      const int t0 = na * 16 + 4 * lg;
      *(short4v*)&Ps[s * 128 + (((t0 >> 3) ^ (s & 7)) * 8) + (t0 & 7)] =
          pack4(st[na][nb]);
    }
  __syncthreads();

  // O^T = Vt . P^T : ot[dn][mi], C rows = d, cols = s
  f32x4 ot[4][2] = {};
  __builtin_amdgcn_s_setprio(1);
#pragma unroll
  for (int kt = 0; kt < 4; ++kt) {
    short8 pa[2];
#pragma unroll
    for (int mi = 0; mi < 2; ++mi) {
      int r = w * 32 + mi * 16 + lrow;
      int pc = (kt * 4 + lg) ^ (r & 7);
      pa[mi] = *(const short8*)&Ps[r * 128 + pc * 8];
    }
#pragma unroll
    for (int dn = 0; dn < 4; ++dn) {
      int d = dn * 16 + lrow;
      int pc = (kt * 4 + lg) ^ (d & 7);
      short8 vb = *(const short8*)&Vt[d * 128 + pc * 8];
#pragma unroll
      for (int mi = 0; mi < 2; ++mi)
        ot[dn][mi] = __builtin_amdgcn_mfma_f32_16x16x32_bf16(vb, pa[mi], ot[dn][mi], 0, 0, 0);
    }
  }
  __builtin_amdgcn_s_setprio(0);

  // write attn-out bf16: rows pos = seg*128 + s, cols h*64 + d; d-runs packed b64
#pragma unroll
  for (int dn = 0; dn < 4; ++dn)
#pragma unroll
    for (int mi = 0; mi < 2; ++mi) {
      const int d0 = dn * 16 + 4 * lg;
      const int pos = seg * 128 + w * 32 + mi * 16 + lrow;
      const float iv = inv_sm[mi];
      f32x4 v = ot[dn][mi];
      f32x4 vs = { v[0] * iv, v[1] * iv, v[2] * iv, v[3] * iv };
      *(short4v*)&aout[(size_t)(b * 4096 + pos) * 1024 + h * 64 + d0] = pack4(vs);
    }
}

// ---------------- launch ----------------
extern "C" void kernel_launch(void* const* d_in, const int* in_sizes, int n_in,
                              void* d_out, int out_size, void* d_ws, size_t ws_size,
                              hipStream_t stream) {
  const float* x     = (const float*)d_in[0];
  const float* w_qkv = (const float*)d_in[1];
  const float* w_out = (const float*)d_in[2];
  const int*   perm  = (const int*)d_in[3];

  char* ws = (char*)d_ws;
  short* xp   = (short*)(ws);                               // 16384*1024 bf16 (33.5MB)
  short* wq   = (short*)(ws + 33554432);                    // 3072*1024  (6.3MB)
  short* wo   = (short*)(ws + 33554432 + 6291456);          // 1024*1024  (2.1MB)
  short* qkvb = (short*)(ws + 41943040);                    // 3*4*16*4096*64 (100.7MB)
  short* aout = xp;  // xp is dead after GEMM1 -> reuse for attention output

  k_gather_cast<<<16384, 256, 0, stream>>>(x, perm, xp);
  k_cast<<<3072, 256, 0, stream>>>(w_qkv, wq);
  k_cast<<<1024, 256, 0, stream>>>(w_out, wo);
  k_gemm8<0, 12><<<768, 512, 0, stream>>>(xp, wq, qkvb);
  k_attn<<<2048, 256, 0, stream>>>(qkvb, aout);
  k_gemm_s<<<1024, 256, 0, stream>>>(aout, wo, (float*)d_out);
}

// Round 6
// 313.816 us; speedup vs baseline: 1.0244x; 1.0244x over previous
//
#include <hip/hip_runtime.h>
#include <stdint.h>

// B=4, M=4096, HID=1024, H=16, HD=64, SEG=128, nseg=32, DIL=2, SCALE=0.125
// out = ((perm-gathered x) @ Wqkv^T -> segment attention with parity mask) @ Wout^T

typedef __attribute__((ext_vector_type(8))) short short8;
typedef __attribute__((ext_vector_type(4))) short short4v;
typedef __attribute__((ext_vector_type(4))) float f32x4;

#define DEV __device__ __forceinline__

DEV short f2bf(float f) {
  union { float f; uint32_t u; } x; x.f = f;
  uint32_t r = x.u + 0x7fffu + ((x.u >> 16) & 1u);
  return (short)(r >> 16);
}

DEV short4v pack4(f32x4 v) {
  short4v o = { f2bf(v[0]), f2bf(v[1]), f2bf(v[2]), f2bf(v[3]) };
  return o;
}

DEV void gload_lds16(const void* g, void* l) {
  __builtin_amdgcn_global_load_lds(
      (const __attribute__((address_space(1))) uint32_t*)g,
      (__attribute__((address_space(3))) uint32_t*)l, 16, 0, 0);
}

#define BAR() __builtin_amdgcn_s_barrier()
#define LGKM0() do { asm volatile("s_waitcnt lgkmcnt(0)" ::: "memory"); \
                     __builtin_amdgcn_sched_barrier(0); } while (0)
#define VMC(n) asm volatile("s_waitcnt vmcnt(" #n ")" ::: "memory")

// ---------------- converts ----------------
__global__ __launch_bounds__(256) void k_gather_cast(
    const float* __restrict__ x, const int* __restrict__ perm, short* __restrict__ xp) {
  const int row = blockIdx.x;             // b*4096 + pos (permuted order)
  const int b = row >> 12, pos = row & 4095;
  const int src = (b << 12) + perm[pos];
  const f32x4 v = ((const f32x4*)(x + (size_t)src * 1024))[threadIdx.x];
  ((short4v*)(xp + (size_t)row * 1024))[threadIdx.x] = pack4(v);
}

__global__ __launch_bounds__(256) void k_cast(
    const float* __restrict__ src, short* __restrict__ dst) {
  const int i = blockIdx.x * 256 + threadIdx.x;
  const f32x4 v = ((const f32x4*)src)[i];
  ((short4v*)dst)[i] = pack4(v);
}

// ---------------- 256x256 8-phase GEMM (GEMM1): C = A(MxK) * W(NxK)^T, K=1024 ----------------
// ROUND-2 configuration (proven 109us): 8 waves 2(M)x4(N), mfma(af,bfrag),
// acc[mh][mi][nh][ni], depth-2 prefetch vmcnt(4), scalar scatter epilogue.
// LDS: 2 dbuf x (A 256x64 + B 256x64) bf16 = 128 KiB, T2-swizzled via pre-swizzled src.
// EPI==0: scatter bf16 into qkv ws (3,B,H,M,HD).
template <int EPI, int NBJ>
__global__ __launch_bounds__(512, 2) void k_gemm8(
    const short* __restrict__ A, const short* __restrict__ W, void* __restrict__ Cout) {
  __shared__ __attribute__((aligned(16))) short lds[65536];   // 128 KiB
  const int tid = threadIdx.x;
  const int lane = tid & 63, w = tid >> 6;
  const int wr = w >> 2, wc = w & 3;
  const int lrow = lane & 15, lg = lane >> 4;

  // XCD-aware swizzle (grid = NBJ*64, divisible by 8)
  const int nwg = NBJ * 64;
  const int cpx = nwg >> 3;
  const int bid = blockIdx.x;
  const int sw = (bid & 7) * cpx + (bid >> 3);
  const int bi = sw / NBJ, bj = sw % NBJ;

  const short* Abase = A + (size_t)bi * 256 * 1024;
  const short* Bbase = W + (size_t)bj * 256 * 1024;

  // staging: 2 x 16B chunks per thread per 128x64 half-tile
  const int c0 = tid, c1 = tid + 512;
  const int sOff0 = (c0 >> 3) * 1024 + (((c0 & 7) ^ ((c0 >> 3) & 7)) * 8);
  const int sOff1 = (c1 >> 3) * 1024 + (((c1 & 7) ^ ((c1 >> 3) & 7)) * 8);
  const int pc0 = lg ^ (lrow & 7), pc1 = (4 + lg) ^ (lrow & 7);

  f32x4 acc[2][4][2][2] = {};   // [mh][mi][nh][ni]
  short8 af[4][2], bfrag[2][2][2];

#define ISSUE(base, half, tile, isB) do {                                   \
    const short* _s = (base) + (half) * (128 * 1024) + (tile) * 64;         \
    short* _d = lds + (((tile) & 1) * 32768) + (isB) * 16384 + (half) * 8192; \
    gload_lds16(_s + sOff0, _d + c0 * 8);                                   \
    gload_lds16(_s + sOff1, _d + c1 * 8);                                   \
  } while (0)

#define LDA(mh) do {                                                        \
    const short* _b = ldsbuf + (mh) * 8192;                                 \
    _Pragma("unroll") for (int mi = 0; mi < 4; ++mi) {                      \
      const short* _r = _b + (wr * 64 + mi * 16 + lrow) * 64;               \
      af[mi][0] = *(const short8*)(_r + pc0 * 8);                           \
      af[mi][1] = *(const short8*)(_r + pc1 * 8); } } while (0)

#define LDB(nh) do {                                                        \
    const short* _b = ldsbuf + 16384 + (nh) * 8192;                         \
    _Pragma("unroll") for (int ni = 0; ni < 2; ++ni) {                      \
      const short* _r = _b + (wc * 32 + ni * 16 + lrow) * 64;               \
      bfrag[nh][ni][0] = *(const short8*)(_r + pc0 * 8);                    \
      bfrag[nh][ni][1] = *(const short8*)(_r + pc1 * 8); } } while (0)

#define MM(mh, nh) do {                                                     \
    _Pragma("unroll") for (int mi = 0; mi < 4; ++mi)                        \
    _Pragma("unroll") for (int ni = 0; ni < 2; ++ni) {                      \
      acc[mh][mi][nh][ni] = __builtin_amdgcn_mfma_f32_16x16x32_bf16(        \
          af[mi][0], bfrag[nh][ni][0], acc[mh][mi][nh][ni], 0, 0, 0);       \
      acc[mh][mi][nh][ni] = __builtin_amdgcn_mfma_f32_16x16x32_bf16(        \
          af[mi][1], bfrag[nh][ni][1], acc[mh][mi][nh][ni], 0, 0, 0); } } while (0)

  // prologue: tile0 {A0,B0,A1,B1} + tile1 {A0,B0}; wait tile0, 2 half-tiles in flight
  ISSUE(Abase, 0, 0, 0); ISSUE(Bbase, 0, 0, 1);
  ISSUE(Abase, 1, 0, 0); ISSUE(Bbase, 1, 0, 1);
  ISSUE(Abase, 0, 1, 0); ISSUE(Bbase, 0, 1, 1);
  VMC(4);
  BAR();

#pragma unroll 2
  for (int t = 0; t < 16; ++t) {
    const short* ldsbuf = lds + ((t & 1) * 32768);
    // ph1: (mh0,nh0); prefetch A1(t+1)
    LDA(0); LDB(0);
    if (t < 15) ISSUE(Abase, 1, t + 1, 0);
    BAR(); LGKM0();
    __builtin_amdgcn_s_setprio(1); MM(0, 0); __builtin_amdgcn_s_setprio(0);
    BAR();
    // ph2: (mh0,nh1); prefetch B1(t+1)
    LDB(1);
    if (t < 15) ISSUE(Bbase, 1, t + 1, 1);
    BAR(); LGKM0();
    __builtin_amdgcn_s_setprio(1); MM(0, 1); __builtin_amdgcn_s_setprio(0);
    BAR();
    // ph3: (mh1,nh0); prefetch A0(t+2) into current buf (A0 LDS dead since ph1)
    LDA(1);
    if (t < 14) ISSUE(Abase, 0, t + 2, 0);
    BAR(); LGKM0();
    __builtin_amdgcn_s_setprio(1); MM(1, 0); __builtin_amdgcn_s_setprio(0);
    BAR();
    // ph4: (mh1,nh1); prefetch B0(t+2); counted vmcnt(4) certifies tile t+1 resident
    if (t < 14) ISSUE(Bbase, 0, t + 2, 1);
    BAR(); LGKM0();
    __builtin_amdgcn_s_setprio(1); MM(1, 1); __builtin_amdgcn_s_setprio(0);
    if (t < 14) { VMC(4); } else { VMC(0); }
    BAR();
  }
#undef ISSUE
#undef LDA
#undef LDB
#undef MM

  if (EPI == 0) {
    short* Q = (short*)Cout;
#pragma unroll
    for (int mh = 0; mh < 2; ++mh)
#pragma unroll
    for (int mi = 0; mi < 4; ++mi)
#pragma unroll
    for (int reg = 0; reg < 4; ++reg) {
      const int gr = bi * 256 + mh * 128 + wr * 64 + mi * 16 + 4 * lg + reg;
      const int b = gr >> 12, pos = gr & 4095;
#pragma unroll
      for (int nh = 0; nh < 2; ++nh)
#pragma unroll
      for (int ni = 0; ni < 2; ++ni) {
        const int gc = bj * 256 + nh * 128 + wc * 32 + ni * 16 + lrow;
        const int sel = gc >> 10, h = (gc >> 6) & 15, d = gc & 63;
        Q[((((size_t)sel * 4 + b) * 16 + h) * 4096 + pos) * 64 + d] =
            f2bf(acc[mh][mi][nh][ni][reg]);
      }
    }
  } else {
    float* C = (float*)Cout;
#pragma unroll
    for (int mh = 0; mh < 2; ++mh)
#pragma unroll
    for (int mi = 0; mi < 4; ++mi)
#pragma unroll
    for (int reg = 0; reg < 4; ++reg) {
      const int gr = bi * 256 + mh * 128 + wr * 64 + mi * 16 + 4 * lg + reg;
#pragma unroll
      for (int nh = 0; nh < 2; ++nh)
#pragma unroll
      for (int ni = 0; ni < 2; ++ni) {
        const int gc = bj * 256 + nh * 128 + wc * 32 + ni * 16 + lrow;
        C[(size_t)gr * 1024 + gc] = acc[mh][mi][nh][ni][reg];
      }
    }
  }
}

// ---------------- 128x128 m97-style GEMM (GEMM2): C = A(16384xK) * W(1024xK)^T fp32 ----------------
// 4 waves, BK=64, single LDS buffer, syncthreads-bracketed gload_lds (m97 structure).
// NORMAL operand order (round-1-proven): mfma(af, bf), scalar fp32 epilogue.
// Grid 1024 = 3 blocks/CU -> inter-block overlap covers the barrier drain.
__global__ __launch_bounds__(256, 3) void k_gemm_s(
    const short* __restrict__ A, const short* __restrict__ W, float* __restrict__ C) {
  __shared__ __attribute__((aligned(16))) short As[128 * 64];
  __shared__ __attribute__((aligned(16))) short Bs[128 * 64];
  const int tid = threadIdx.x;
  const int lane = tid & 63, w = tid >> 6;
  const int wr = w >> 1, wc = w & 1;
  const int lrow = lane & 15, lg = lane >> 4;
  // XCD swizzle over grid 1024; within an XCD chunk, all bj for a bi (A-panel L2 reuse)
  const int bid = blockIdx.x;
  const int sw = (bid & 7) * 128 + (bid >> 3);
  const int bi = sw >> 3, bj = sw & 7;

  f32x4 acc[4][4] = {};   // [mi][ni]
  const size_t arow0 = (size_t)bi * 128;
  const size_t brow0 = (size_t)bj * 128;

  for (int k0 = 0; k0 < 1024; k0 += 64) {
    __syncthreads();
#pragma unroll
    for (int i = 0; i < 4; ++i) {
      int c = i * 256 + tid;
      int row = c >> 3, ch = c & 7, g = ch ^ (row & 7);
      gload_lds16(A + (arow0 + row) * 1024 + k0 + g * 8, &As[c * 8]);
      gload_lds16(W + (brow0 + row) * 1024 + k0 + g * 8, &Bs[c * 8]);
    }
    __syncthreads();
#pragma unroll
    for (int kk = 0; kk < 2; ++kk) {
      short8 af[4], bf[4];
#pragma unroll
      for (int mi = 0; mi < 4; ++mi) {
        int r = wr * 64 + mi * 16 + lrow;
        int pc = (kk * 4 + lg) ^ (r & 7);
        af[mi] = *(const short8*)&As[r * 64 + pc * 8];
      }
#pragma unroll
      for (int ni = 0; ni < 4; ++ni) {
        int r = wc * 64 + ni * 16 + lrow;
        int pc = (kk * 4 + lg) ^ (r & 7);
        bf[ni] = *(const short8*)&Bs[r * 64 + pc * 8];
      }
#pragma unroll
      for (int mi = 0; mi < 4; ++mi)
#pragma unroll
        for (int ni = 0; ni < 4; ++ni)
          acc[mi][ni] = __builtin_amdgcn_mfma_f32_16x16x32_bf16(
              af[mi], bf[ni], acc[mi][ni], 0, 0, 0);
    }
  }
#pragma unroll
  for (int mi = 0; mi < 4; ++mi)
#pragma unroll
    for (int reg = 0; reg < 4; ++reg) {
      const int gr = bi * 128 + wr * 64 + mi * 16 + 4 * lg + reg;
#pragma unroll
      for (int ni = 0; ni < 4; ++ni) {
        const int gc = bj * 128 + wc * 64 + ni * 16 + lrow;
        C[(size_t)gr * 1024 + gc] = acc[mi][ni][reg];
      }
    }
}

// ---------------- segment attention ----------------
// one block per (b,h,seg). S^T = mfma(K,Q): lane holds t = na*16+4lg+reg (4-runs),
// s = w*32+nb*16+lrow. Softmax over t = in-lane tree + shfl_xor(16,32).
// P stored row-major [s][t] with packed b64 (t-runs are contiguous), swizzled.
// O^T = mfma(Vt, P): lane holds d-runs -> packed b64 epilogue; inv is lane-local.
__global__ __launch_bounds__(256, 3) void k_attn(
    const short* __restrict__ qkv, short* __restrict__ aout) {
  __shared__ __attribute__((aligned(16))) short smem[24576];
  short* Qs = smem;
  short* Ks = smem + 8192;
  short* Vt = smem + 16384;   // transposed [d][t]
  short* Ps = smem;           // alias over Qs+Ks (dead after QK^T)
  const int bid = blockIdx.x;
  const int seg = bid & 31, h = (bid >> 5) & 15, b = bid >> 9;
  const size_t plane = (size_t)4096 * 64;
  const short* qp = qkv + ((size_t)(0 * 4 + b) * 16 + h) * plane + seg * 128 * 64;
  const short* kp = qkv + ((size_t)(1 * 4 + b) * 16 + h) * plane + seg * 128 * 64;
  const short* vp = qkv + ((size_t)(2 * 4 + b) * 16 + h) * plane + seg * 128 * 64;
  const int tid = threadIdx.x, lane = tid & 63, w = tid >> 6;
  const int lrow = lane & 15, lg = lane >> 4;

#pragma unroll
  for (int i = 0; i < 4; ++i) {
    int c = i * 256 + tid;
    int row = c >> 3, ch = c & 7, g = ch ^ (row & 7);
    gload_lds16(qp + row * 64 + g * 8, &Qs[c * 8]);
    gload_lds16(kp + row * 64 + g * 8, &Ks[c * 8]);
  }
  // V: coalesced 16B global loads, transposed+swizzled LDS writes
#pragma unroll
  for (int i = 0; i < 4; ++i) {
    int c = i * 256 + tid;
    int t = c >> 3, d0 = (c & 7) * 8;
    short8 v = *(const short8*)(vp + t * 64 + d0);
#pragma unroll
    for (int j = 0; j < 8; ++j) {
      int d = d0 + j;
      Vt[d * 128 + (t ^ ((d & 7) * 8))] = v[j];
    }
  }
  __syncthreads();

  // S^T = K Q^T : st[na][nb], C rows = t (K-side), cols = s (Q-side)
  f32x4 st[8][2] = {};
  __builtin_amdgcn_s_setprio(1);
#pragma unroll
  for (int kk = 0; kk < 2; ++kk) {
    short8 qb[2];
#pragma unroll
    for (int nb = 0; nb < 2; ++nb) {
      int r = w * 32 + nb * 16 + lrow;
      int pc = (kk * 4 + lg) ^ (r & 7);
      qb[nb] = *(const short8*)&Qs[r * 64 + pc * 8];
    }
#pragma unroll
    for (int na = 0; na < 8; ++na) {
      int r = na * 16 + lrow;
      int pc = (kk * 4 + lg) ^ (r & 7);
      short8 ka = *(const short8*)&Ks[r * 64 + pc * 8];
#pragma unroll
      for (int nb = 0; nb < 2; ++nb)
        st[na][nb] = __builtin_amdgcn_mfma_f32_16x16x32_bf16(ka, qb[nb], st[na][nb], 0, 0, 0);
    }
  }
  __builtin_amdgcn_s_setprio(0);

  // masked softmax over t (per lane: 32 t-values per s; s parity = lrow&1, t parity = reg&1)
  float inv_sm[2];
  const int oddS = lrow & 1;
#pragma unroll
  for (int nb = 0; nb < 2; ++nb) {
    float pm = -3.0e38f;
#pragma unroll
    for (int na = 0; na < 8; ++na)
#pragma unroll
      for (int reg = 0; reg < 4; ++reg) {
        float v = st[na][nb][reg] * 0.125f;
        if (oddS && (reg & 1)) v = -1.0e30f;
        st[na][nb][reg] = v;
        pm = fmaxf(pm, v);
      }
    pm = fmaxf(pm, __shfl_xor(pm, 16));
    pm = fmaxf(pm, __shfl_xor(pm, 32));
    float sum = 0.f;
#pragma unroll
    for (int na = 0; na < 8; ++na)
#pragma unroll
      for (int reg = 0; reg < 4; ++reg) {
        float p = __expf(st[na][nb][reg] - pm);
        st[na][nb][reg] = p;
        sum += p;
      }
    sum += __shfl_xor(sum, 16);
    sum += __shfl_xor(sum, 32);
    inv_sm[nb] = 1.0f / sum;
  }

  __syncthreads();   // all QK^T LDS reads done before Ps overwrites Qs/Ks

  // store P row-major [s][128 t], packed b64 (4 consecutive t per frag), swizzled
#pragma unroll
  for (int na = 0; na < 8; ++na)
#pragma unroll
    for (int nb = 0; nb < 2; ++nb) {
      const int s = w * 32 + nb * 16 + lrow;
      const int t0 = na * 16 + 4 * lg;
      *(short4v*)&Ps[s * 128 + (((t0 >> 3) ^ (s & 7)) * 8) + (t0 & 7)] =
          pack4(st[na][nb]);
    }
  __syncthreads();

  // O^T = Vt . P^T : ot[dn][mi], C rows = d, cols = s
  f32x4 ot[4][2] = {};
  __builtin_amdgcn_s_setprio(1);
#pragma unroll
  for (int kt = 0; kt < 4; ++kt) {
    short8 pa[2];
#pragma unroll
    for (int mi = 0; mi < 2; ++mi) {
      int r = w * 32 + mi * 16 + lrow;
      int pc = (kt * 4 + lg) ^ (r & 7);
      pa[mi] = *(const short8*)&Ps[r * 128 + pc * 8];
    }
#pragma unroll
    for (int dn = 0; dn < 4; ++dn) {
      int d = dn * 16 + lrow;
      int pc = (kt * 4 + lg) ^ (d & 7);
      short8 vb = *(const short8*)&Vt[d * 128 + pc * 8];
#pragma unroll
      for (int mi = 0; mi < 2; ++mi)
        ot[dn][mi] = __builtin_amdgcn_mfma_f32_16x16x32_bf16(vb, pa[mi], ot[dn][mi], 0, 0, 0);
    }
  }
  __builtin_amdgcn_s_setprio(0);

  // write attn-out bf16: rows pos = seg*128 + s, cols h*64 + d; d-runs packed b64
#pragma unroll
  for (int dn = 0; dn < 4; ++dn)
#pragma unroll
    for (int mi = 0; mi < 2; ++mi) {
      const int d0 = dn * 16 + 4 * lg;
      const int pos = seg * 128 + w * 32 + mi * 16 + lrow;
      const float iv = inv_sm[mi];
      f32x4 v = ot[dn][mi];
      f32x4 vs = { v[0] * iv, v[1] * iv, v[2] * iv, v[3] * iv };
      *(short4v*)&aout[(size_t)(b * 4096 + pos) * 1024 + h * 64 + d0] = pack4(vs);
    }
}

// ---------------- launch ----------------
extern "C" void kernel_launch(void* const* d_in, const int* in_sizes, int n_in,
                              void* d_out, int out_size, void* d_ws, size_t ws_size,
                              hipStream_t stream) {
  const float* x     = (const float*)d_in[0];
  const float* w_qkv = (const float*)d_in[1];
  const float* w_out = (const float*)d_in[2];
  const int*   perm  = (const int*)d_in[3];

  char* ws = (char*)d_ws;
  short* xp   = (short*)(ws);                               // 16384*1024 bf16 (33.5MB)
  short* wq   = (short*)(ws + 33554432);                    // 3072*1024  (6.3MB)
  short* wo   = (short*)(ws + 33554432 + 6291456);          // 1024*1024  (2.1MB)
  short* qkvb = (short*)(ws + 41943040);                    // 3*4*16*4096*64 (100.7MB)
  short* aout = xp;  // xp is dead after GEMM1 -> reuse for attention output

  k_gather_cast<<<16384, 256, 0, stream>>>(x, perm, xp);
  k_cast<<<3072, 256, 0, stream>>>(w_qkv, wq);
  k_cast<<<1024, 256, 0, stream>>>(w_out, wo);
  k_gemm8<0, 12><<<768, 512, 0, stream>>>(xp, wq, qkvb);
  k_attn<<<2048, 256, 0, stream>>>(qkvb, aout);
  k_gemm_s<<<1024, 256, 0, stream>>>(aout, wo, (float*)d_out);
}

// Round 7
// 310.836 us; speedup vs baseline: 1.0342x; 1.0096x over previous
//
#include <hip/hip_runtime.h>
#include <stdint.h>

// B=4, M=4096, HID=1024, H=16, HD=64, SEG=128, nseg=32, DIL=2, SCALE=0.125
// out = ((perm-gathered x) @ Wqkv^T -> segment attention with parity mask) @ Wout^T

typedef __attribute__((ext_vector_type(8))) short short8;
typedef __attribute__((ext_vector_type(4))) short short4v;
typedef __attribute__((ext_vector_type(4))) float f32x4;

#define DEV __device__ __forceinline__

DEV short f2bf(float f) {
  union { float f; uint32_t u; } x; x.f = f;
  uint32_t r = x.u + 0x7fffu + ((x.u >> 16) & 1u);
  return (short)(r >> 16);
}

DEV short4v pack4(f32x4 v) {
  short4v o = { f2bf(v[0]), f2bf(v[1]), f2bf(v[2]), f2bf(v[3]) };
  return o;
}

DEV void gload_lds16(const void* g, void* l) {
  __builtin_amdgcn_global_load_lds(
      (const __attribute__((address_space(1))) uint32_t*)g,
      (__attribute__((address_space(3))) uint32_t*)l, 16, 0, 0);
}

#define BAR() __builtin_amdgcn_s_barrier()
#define LGKM0() do { asm volatile("s_waitcnt lgkmcnt(0)" ::: "memory"); \
                     __builtin_amdgcn_sched_barrier(0); } while (0)
#define VMC(n) asm volatile("s_waitcnt vmcnt(" #n ")" ::: "memory")

// ---------------- converts ----------------
__global__ __launch_bounds__(256) void k_gather_cast(
    const float* __restrict__ x, const int* __restrict__ perm, short* __restrict__ xp) {
  const int row = blockIdx.x;             // b*4096 + pos (permuted order)
  const int b = row >> 12, pos = row & 4095;
  const int src = (b << 12) + perm[pos];
  const f32x4 v = ((const f32x4*)(x + (size_t)src * 1024))[threadIdx.x];
  ((short4v*)(xp + (size_t)row * 1024))[threadIdx.x] = pack4(v);
}

__global__ __launch_bounds__(256) void k_cast(
    const float* __restrict__ src, short* __restrict__ dst) {
  const int i = blockIdx.x * 256 + threadIdx.x;
  const f32x4 v = ((const f32x4*)src)[i];
  ((short4v*)dst)[i] = pack4(v);
}

// ---------------- 256x256 8-phase GEMM (GEMM1): C = A(MxK) * W(NxK)^T, K=1024 ----------------
// ROUND-2 configuration (proven 109us): 8 waves 2(M)x4(N), mfma(af,bfrag),
// acc[mh][mi][nh][ni], depth-2 prefetch vmcnt(4), scalar scatter epilogue.
// LDS: 2 dbuf x (A 256x64 + B 256x64) bf16 = 128 KiB, T2-swizzled via pre-swizzled src.
// EPI==0: scatter bf16 into qkv ws (3,B,H,M,HD).
template <int EPI, int NBJ>
__global__ __launch_bounds__(512, 2) void k_gemm8(
    const short* __restrict__ A, const short* __restrict__ W, void* __restrict__ Cout) {
  __shared__ __attribute__((aligned(16))) short lds[65536];   // 128 KiB
  const int tid = threadIdx.x;
  const int lane = tid & 63, w = tid >> 6;
  const int wr = w >> 2, wc = w & 3;
  const int lrow = lane & 15, lg = lane >> 4;

  // XCD-aware swizzle (grid = NBJ*64, divisible by 8)
  const int nwg = NBJ * 64;
  const int cpx = nwg >> 3;
  const int bid = blockIdx.x;
  const int sw = (bid & 7) * cpx + (bid >> 3);
  const int bi = sw / NBJ, bj = sw % NBJ;

  const short* Abase = A + (size_t)bi * 256 * 1024;
  const short* Bbase = W + (size_t)bj * 256 * 1024;

  // staging: 2 x 16B chunks per thread per 128x64 half-tile
  const int c0 = tid, c1 = tid + 512;
  const int sOff0 = (c0 >> 3) * 1024 + (((c0 & 7) ^ ((c0 >> 3) & 7)) * 8);
  const int sOff1 = (c1 >> 3) * 1024 + (((c1 & 7) ^ ((c1 >> 3) & 7)) * 8);
  const int pc0 = lg ^ (lrow & 7), pc1 = (4 + lg) ^ (lrow & 7);

  f32x4 acc[2][4][2][2] = {};   // [mh][mi][nh][ni]
  short8 af[4][2], bfrag[2][2][2];

#define ISSUE(base, half, tile, isB) do {                                   \
    const short* _s = (base) + (half) * (128 * 1024) + (tile) * 64;         \
    short* _d = lds + (((tile) & 1) * 32768) + (isB) * 16384 + (half) * 8192; \
    gload_lds16(_s + sOff0, _d + c0 * 8);                                   \
    gload_lds16(_s + sOff1, _d + c1 * 8);                                   \
  } while (0)

#define LDA(mh) do {                                                        \
    const short* _b = ldsbuf + (mh) * 8192;                                 \
    _Pragma("unroll") for (int mi = 0; mi < 4; ++mi) {                      \
      const short* _r = _b + (wr * 64 + mi * 16 + lrow) * 64;               \
      af[mi][0] = *(const short8*)(_r + pc0 * 8);                           \
      af[mi][1] = *(const short8*)(_r + pc1 * 8); } } while (0)

#define LDB(nh) do {                                                        \
    const short* _b = ldsbuf + 16384 + (nh) * 8192;                         \
    _Pragma("unroll") for (int ni = 0; ni < 2; ++ni) {                      \
      const short* _r = _b + (wc * 32 + ni * 16 + lrow) * 64;               \
      bfrag[nh][ni][0] = *(const short8*)(_r + pc0 * 8);                    \
      bfrag[nh][ni][1] = *(const short8*)(_r + pc1 * 8); } } while (0)

#define MM(mh, nh) do {                                                     \
    _Pragma("unroll") for (int mi = 0; mi < 4; ++mi)                        \
    _Pragma("unroll") for (int ni = 0; ni < 2; ++ni) {                      \
      acc[mh][mi][nh][ni] = __builtin_amdgcn_mfma_f32_16x16x32_bf16(        \
          af[mi][0], bfrag[nh][ni][0], acc[mh][mi][nh][ni], 0, 0, 0);       \
      acc[mh][mi][nh][ni] = __builtin_amdgcn_mfma_f32_16x16x32_bf16(        \
          af[mi][1], bfrag[nh][ni][1], acc[mh][mi][nh][ni], 0, 0, 0); } } while (0)

  // prologue: tile0 {A0,B0,A1,B1} + tile1 {A0,B0}; wait tile0, 2 half-tiles in flight
  ISSUE(Abase, 0, 0, 0); ISSUE(Bbase, 0, 0, 1);
  ISSUE(Abase, 1, 0, 0); ISSUE(Bbase, 1, 0, 1);
  ISSUE(Abase, 0, 1, 0); ISSUE(Bbase, 0, 1, 1);
  VMC(4);
  BAR();

#pragma unroll 2
  for (int t = 0; t < 16; ++t) {
    const short* ldsbuf = lds + ((t & 1) * 32768);
    // ph1: (mh0,nh0); prefetch A1(t+1)
    LDA(0); LDB(0);
    if (t < 15) ISSUE(Abase, 1, t + 1, 0);
    BAR(); LGKM0();
    __builtin_amdgcn_s_setprio(1); MM(0, 0); __builtin_amdgcn_s_setprio(0);
    BAR();
    // ph2: (mh0,nh1); prefetch B1(t+1)
    LDB(1);
    if (t < 15) ISSUE(Bbase, 1, t + 1, 1);
    BAR(); LGKM0();
    __builtin_amdgcn_s_setprio(1); MM(0, 1); __builtin_amdgcn_s_setprio(0);
    BAR();
    // ph3: (mh1,nh0); prefetch A0(t+2) into current buf (A0 LDS dead since ph1)
    LDA(1);
    if (t < 14) ISSUE(Abase, 0, t + 2, 0);
    BAR(); LGKM0();
    __builtin_amdgcn_s_setprio(1); MM(1, 0); __builtin_amdgcn_s_setprio(0);
    BAR();
    // ph4: (mh1,nh1); prefetch B0(t+2); counted vmcnt(4) certifies tile t+1 resident
    if (t < 14) ISSUE(Bbase, 0, t + 2, 1);
    BAR(); LGKM0();
    __builtin_amdgcn_s_setprio(1); MM(1, 1); __builtin_amdgcn_s_setprio(0);
    if (t < 14) { VMC(4); } else { VMC(0); }
    BAR();
  }
#undef ISSUE
#undef LDA
#undef LDB
#undef MM

  if (EPI == 0) {
    short* Q = (short*)Cout;
#pragma unroll
    for (int mh = 0; mh < 2; ++mh)
#pragma unroll
    for (int mi = 0; mi < 4; ++mi)
#pragma unroll
    for (int reg = 0; reg < 4; ++reg) {
      const int gr = bi * 256 + mh * 128 + wr * 64 + mi * 16 + 4 * lg + reg;
      const int b = gr >> 12, pos = gr & 4095;
#pragma unroll
      for (int nh = 0; nh < 2; ++nh)
#pragma unroll
      for (int ni = 0; ni < 2; ++ni) {
        const int gc = bj * 256 + nh * 128 + wc * 32 + ni * 16 + lrow;
        const int sel = gc >> 10, h = (gc >> 6) & 15, d = gc & 63;
        Q[((((size_t)sel * 4 + b) * 16 + h) * 4096 + pos) * 64 + d] =
            f2bf(acc[mh][mi][nh][ni][reg]);
      }
    }
  } else {
    float* C = (float*)Cout;
#pragma unroll
    for (int mh = 0; mh < 2; ++mh)
#pragma unroll
    for (int mi = 0; mi < 4; ++mi)
#pragma unroll
    for (int reg = 0; reg < 4; ++reg) {
      const int gr = bi * 256 + mh * 128 + wr * 64 + mi * 16 + 4 * lg + reg;
#pragma unroll
      for (int nh = 0; nh < 2; ++nh)
#pragma unroll
      for (int ni = 0; ni < 2; ++ni) {
        const int gc = bj * 256 + nh * 128 + wc * 32 + ni * 16 + lrow;
        C[(size_t)gr * 1024 + gc] = acc[mh][mi][nh][ni][reg];
      }
    }
  }
}

// ---------------- 128x128 m97-style GEMM (GEMM2): C = A(16384xK) * W(1024xK)^T fp32 ----------------
// 4 waves, BK=64, single LDS buffer, syncthreads-bracketed gload_lds (m97 structure).
// Grid 1024 with __launch_bounds__(256,4): exactly 4 blocks/CU, all co-resident (no tail).
__global__ __launch_bounds__(256, 4) void k_gemm_s(
    const short* __restrict__ A, const short* __restrict__ W, float* __restrict__ C) {
  __shared__ __attribute__((aligned(16))) short As[128 * 64];
  __shared__ __attribute__((aligned(16))) short Bs[128 * 64];
  const int tid = threadIdx.x;
  const int lane = tid & 63, w = tid >> 6;
  const int wr = w >> 1, wc = w & 1;
  const int lrow = lane & 15, lg = lane >> 4;
  // XCD swizzle over grid 1024; within an XCD chunk, all bj for a bi (A-panel L2 reuse)
  const int bid = blockIdx.x;
  const int sw = (bid & 7) * 128 + (bid >> 3);
  const int bi = sw >> 3, bj = sw & 7;

  f32x4 acc[4][4] = {};   // [mi][ni]
  const size_t arow0 = (size_t)bi * 128;
  const size_t brow0 = (size_t)bj * 128;

  for (int k0 = 0; k0 < 1024; k0 += 64) {
    __syncthreads();
#pragma unroll
    for (int i = 0; i < 4; ++i) {
      int c = i * 256 + tid;
      int row = c >> 3, ch = c & 7, g = ch ^ (row & 7);
      gload_lds16(A + (arow0 + row) * 1024 + k0 + g * 8, &As[c * 8]);
      gload_lds16(W + (brow0 + row) * 1024 + k0 + g * 8, &Bs[c * 8]);
    }
    __syncthreads();
#pragma unroll
    for (int kk = 0; kk < 2; ++kk) {
      short8 af[4], bf[4];
#pragma unroll
      for (int mi = 0; mi < 4; ++mi) {
        int r = wr * 64 + mi * 16 + lrow;
        int pc = (kk * 4 + lg) ^ (r & 7);
        af[mi] = *(const short8*)&As[r * 64 + pc * 8];
      }
#pragma unroll
      for (int ni = 0; ni < 4; ++ni) {
        int r = wc * 64 + ni * 16 + lrow;
        int pc = (kk * 4 + lg) ^ (r & 7);
        bf[ni] = *(const short8*)&Bs[r * 64 + pc * 8];
      }
#pragma unroll
      for (int mi = 0; mi < 4; ++mi)
#pragma unroll
        for (int ni = 0; ni < 4; ++ni)
          acc[mi][ni] = __builtin_amdgcn_mfma_f32_16x16x32_bf16(
              af[mi], bf[ni], acc[mi][ni], 0, 0, 0);
    }
  }
#pragma unroll
  for (int mi = 0; mi < 4; ++mi)
#pragma unroll
    for (int reg = 0; reg < 4; ++reg) {
      const int gr = bi * 128 + wr * 64 + mi * 16 + 4 * lg + reg;
#pragma unroll
      for (int ni = 0; ni < 4; ++ni) {
        const int gc = bj * 128 + wc * 64 + ni * 16 + lrow;
        C[(size_t)gr * 1024 + gc] = acc[mi][ni][reg];
      }
    }
}

// ---------------- segment attention v2 ----------------
// one block per (b,h,seg). Q in REGISTERS (wave-private fragments); K,V in LDS.
// S^T = mfma(K,Q): lane holds t-runs; softmax over t = in-lane + shfl_xor(16,32).
// Ps (32KB) aliases Ks + scratch; Vt separate. 2 barriers total:
//   stage(K,V) -> BAR -> QK + softmax -> BAR -> Pstore -> PV (own-slice, wave-ordered) -> write
__global__ __launch_bounds__(256, 3) void k_attn(
    const short* __restrict__ qkv, short* __restrict__ aout) {
  __shared__ __attribute__((aligned(16))) short smem[24576];  // 48 KB
  short* Ks = smem;            // bytes [0,16K)
  short* Ps = smem;            // bytes [0,32K) after QK (Ks dead + scratch region)
  short* Vt = smem + 16384;    // bytes [32K,48K), transposed [d][t]
  const int bid = blockIdx.x;
  const int seg = bid & 31, h = (bid >> 5) & 15, b = bid >> 9;
  const size_t plane = (size_t)4096 * 64;
  const short* qp = qkv + ((size_t)(0 * 4 + b) * 16 + h) * plane + seg * 128 * 64;
  const short* kp = qkv + ((size_t)(1 * 4 + b) * 16 + h) * plane + seg * 128 * 64;
  const short* vp = qkv + ((size_t)(2 * 4 + b) * 16 + h) * plane + seg * 128 * 64;
  const int tid = threadIdx.x, lane = tid & 63, w = tid >> 6;
  const int lrow = lane & 15, lg = lane >> 4;

  // stage K via async gload_lds (swizzled source, linear dest)
#pragma unroll
  for (int i = 0; i < 4; ++i) {
    int c = i * 256 + tid;
    int row = c >> 3, ch = c & 7, g = ch ^ (row & 7);
    gload_lds16(kp + row * 64 + g * 8, &Ks[c * 8]);
  }
  // V -> regs (coalesced 16B), Q-frags -> regs (overlap with K staging in flight)
  short8 vreg[4];
#pragma unroll
  for (int i = 0; i < 4; ++i) {
    int c = i * 256 + tid;
    vreg[i] = *(const short8*)(vp + (c >> 3) * 64 + (c & 7) * 8);
  }
  short8 qb[2][2];   // [nb][kk] : rows w*32+nb*16+lrow, k-chunk kk*4+lg
#pragma unroll
  for (int nb = 0; nb < 2; ++nb)
#pragma unroll
    for (int kk = 0; kk < 2; ++kk)
      qb[nb][kk] = *(const short8*)(qp + (w * 32 + nb * 16 + lrow) * 64 + (kk * 4 + lg) * 8);
  // V transpose-writes into Vt (swizzled; ~2-way conflicts = free)
#pragma unroll
  for (int i = 0; i < 4; ++i) {
    int c = i * 256 + tid;
    int t = c >> 3, d0 = (c & 7) * 8;
#pragma unroll
    for (int j = 0; j < 8; ++j) {
      int d = d0 + j;
      Vt[d * 128 + (t ^ ((d & 7) * 8))] = vreg[i][j];
    }
  }
  __syncthreads();   // K resident (gload tracked by vmcnt), Vt written

  // S^T = K Q^T : st[na][nb], C rows = t (K-side), cols = s (Q-side)
  f32x4 st[8][2] = {};
  __builtin_amdgcn_s_setprio(1);
#pragma unroll
  for (int kk = 0; kk < 2; ++kk) {
#pragma unroll
    for (int na = 0; na < 8; ++na) {
      int r = na * 16 + lrow;
      int pc = (kk * 4 + lg) ^ (r & 7);
      short8 ka = *(const short8*)&Ks[r * 64 + pc * 8];
#pragma unroll
      for (int nb = 0; nb < 2; ++nb)
        st[na][nb] = __builtin_amdgcn_mfma_f32_16x16x32_bf16(ka, qb[nb][kk], st[na][nb], 0, 0, 0);
    }
  }
  __builtin_amdgcn_s_setprio(0);

  // masked softmax over t (per lane: 32 t per s; s parity = lrow&1, t parity = reg&1)
  float inv_sm[2];
  const int oddS = lrow & 1;
#pragma unroll
  for (int nb = 0; nb < 2; ++nb) {
    float pm = -3.0e38f;
#pragma unroll
    for (int na = 0; na < 8; ++na)
#pragma unroll
      for (int reg = 0; reg < 4; ++reg) {
        float v = st[na][nb][reg] * 0.125f;
        if (oddS && (reg & 1)) v = -1.0e30f;
        st[na][nb][reg] = v;
        pm = fmaxf(pm, v);
      }
    pm = fmaxf(pm, __shfl_xor(pm, 16));
    pm = fmaxf(pm, __shfl_xor(pm, 32));
    float sum = 0.f;
#pragma unroll
    for (int na = 0; na < 8; ++na)
#pragma unroll
      for (int reg = 0; reg < 4; ++reg) {
        float p = __expf(st[na][nb][reg] - pm);
        st[na][nb][reg] = p;
        sum += p;
      }
    sum += __shfl_xor(sum, 16);
    sum += __shfl_xor(sum, 32);
    inv_sm[nb] = 1.0f / sum;
  }

  __syncthreads();   // all K-reads done before Ps overwrites Ks region

  // store P row-major [s][128 t], packed b64, swizzled; wave writes/reads ONLY its
  // own 32-row slice -> within-wave LDS ordering suffices, no barrier needed after.
#pragma unroll
  for (int na = 0; na < 8; ++na)
#pragma unroll
    for (int nb = 0; nb < 2; ++nb) {
      const int s = w * 32 + nb * 16 + lrow;
      const int t0 = na * 16 + 4 * lg;
      *(short4v*)&Ps[s * 128 + (((t0 >> 3) ^ (s & 7)) * 8) + (t0 & 7)] =
          pack4(st[na][nb]);
    }

  // O^T = Vt . P^T : ot[dn][mi], C rows = d, cols = s
  f32x4 ot[4][2] = {};
  __builtin_amdgcn_s_setprio(1);
#pragma unroll
  for (int kt = 0; kt < 4; ++kt) {
    short8 pa[2];
#pragma unroll
    for (int mi = 0; mi < 2; ++mi) {
      int r = w * 32 + mi * 16 + lrow;
      int pc = (kt * 4 + lg) ^ (r & 7);
      pa[mi] = *(const short8*)&Ps[r * 128 + pc * 8];
    }
#pragma unroll
    for (int dn = 0; dn < 4; ++dn) {
      int d = dn * 16 + lrow;
      int pc = (kt * 4 + lg) ^ (d & 7);
      short8 vb = *(const short8*)&Vt[d * 128 + pc * 8];
#pragma unroll
      for (int mi = 0; mi < 2; ++mi)
        ot[dn][mi] = __builtin_amdgcn_mfma_f32_16x16x32_bf16(vb, pa[mi], ot[dn][mi], 0, 0, 0);
    }
  }
  __builtin_amdgcn_s_setprio(0);

  // write attn-out bf16: rows pos = seg*128 + s, cols h*64 + d; d-runs packed b64
#pragma unroll
  for (int dn = 0; dn < 4; ++dn)
#pragma unroll
    for (int mi = 0; mi < 2; ++mi) {
      const int d0 = dn * 16 + 4 * lg;
      const int pos = seg * 128 + w * 32 + mi * 16 + lrow;
      const float iv = inv_sm[mi];
      f32x4 v = ot[dn][mi];
      f32x4 vs = { v[0] * iv, v[1] * iv, v[2] * iv, v[3] * iv };
      *(short4v*)&aout[(size_t)(b * 4096 + pos) * 1024 + h * 64 + d0] = pack4(vs);
    }
}

// ---------------- launch ----------------
extern "C" void kernel_launch(void* const* d_in, const int* in_sizes, int n_in,
                              void* d_out, int out_size, void* d_ws, size_t ws_size,
                              hipStream_t stream) {
  const float* x     = (const float*)d_in[0];
  const float* w_qkv = (const float*)d_in[1];
  const float* w_out = (const float*)d_in[2];
  const int*   perm  = (const int*)d_in[3];

  char* ws = (char*)d_ws;
  short* xp   = (short*)(ws);                               // 16384*1024 bf16 (33.5MB)
  short* wq   = (short*)(ws + 33554432);                    // 3072*1024  (6.3MB)
  short* wo   = (short*)(ws + 33554432 + 6291456);          // 1024*1024  (2.1MB)
  short* qkvb = (short*)(ws + 41943040);                    // 3*4*16*4096*64 (100.7MB)
  short* aout = xp;  // xp is dead after GEMM1 -> reuse for attention output

  k_gather_cast<<<16384, 256, 0, stream>>>(x, perm, xp);
  k_cast<<<3072, 256, 0, stream>>>(w_qkv, wq);
  k_cast<<<1024, 256, 0, stream>>>(w_out, wo);
  k_gemm8<0, 12><<<768, 512, 0, stream>>>(xp, wq, qkvb);
  k_attn<<<2048, 256, 0, stream>>>(qkvb, aout);
  k_gemm_s<<<1024, 256, 0, stream>>>(aout, wo, (float*)d_out);
}